// Round 1
// baseline (79.686 us; speedup 1.0000x reference)
//
#include <hip/hip_runtime.h>

#define NIMG 8
#define H 2048
#define W 2048
#define AH 64
#define AW 64
#define PAD 992   // (W - AW) / 2

// --- kernel 1: reset flag = (mean(action) == 1.0) ---------------------------
__global__ void carle_flag_kernel(const float* __restrict__ act,
                                  float* __restrict__ flag) {
    __shared__ float sm[256];
    int t = threadIdx.x;
    float s = 0.0f;
    for (int i = t; i < AH * AW; i += 256) s += act[i];
    sm[t] = s;
    __syncthreads();
    for (int k = 128; k > 0; k >>= 1) {
        if (t < k) sm[t] += sm[t + k];
        __syncthreads();
    }
    if (t == 0) flag[0] = (sm[0] == (float)(AH * AW)) ? 1.0f : 0.0f;
}

// --- kernel 2: one Life step (toroidal), action XOR fused at load -----------
__global__ __launch_bounds__(512) void carle_life_kernel(
        const float* __restrict__ uni,
        const float* __restrict__ act,
        const float* __restrict__ flag,
        float* __restrict__ out) {
    __shared__ float sm[3][W];   // rows y-1, y, y+1 (post-XOR)  = 24 KiB

    const int t   = threadIdx.x;        // 0..511
    const int bid = blockIdx.x;         // 0..NIMG*H-1
    const int n   = bid >> 11;          // / H
    const int y   = bid & (H - 1);      // % H
    const int c0  = t << 2;             // first of 4 columns

    const int rows[3] = { (y - 1) & (H - 1), y, (y + 1) & (H - 1) };
    const size_t img = (size_t)n * H * W;

    // stage 3 rows into LDS, XOR action where applicable
    #pragma unroll
    for (int rr = 0; rr < 3; ++rr) {
        const int r = rows[rr];
        float4 v = *reinterpret_cast<const float4*>(uni + img + (size_t)r * W + c0);
        if (r >= PAD && r < PAD + AH && c0 >= PAD && c0 < PAD + AW) {
            const float* a = act + (r - PAD) * AW + (c0 - PAD);
            v.x = (v.x != a[0]) ? 1.0f : 0.0f;
            v.y = (v.y != a[1]) ? 1.0f : 0.0f;
            v.z = (v.z != a[2]) ? 1.0f : 0.0f;
            v.w = (v.w != a[3]) ? 1.0f : 0.0f;
        }
        *reinterpret_cast<float4*>(&sm[rr][c0]) = v;
    }
    __syncthreads();

    // 6-wide windows per row: [c0-1, c0, c0+1, c0+2, c0+3, c0+4] (wrapped)
    float w[3][6];
    #pragma unroll
    for (int rr = 0; rr < 3; ++rr) {
        const float4 v = *reinterpret_cast<const float4*>(&sm[rr][c0]);
        w[rr][0] = sm[rr][(c0 - 1) & (W - 1)];
        w[rr][1] = v.x; w[rr][2] = v.y; w[rr][3] = v.z; w[rr][4] = v.w;
        w[rr][5] = sm[rr][(c0 + 4) & (W - 1)];
    }

    const float keep = (flag[0] == 1.0f) ? 0.0f : 1.0f;

    float4 o;
    float* op = &o.x;
    #pragma unroll
    for (int j = 0; j < 4; ++j) {
        const float top = w[0][j] + w[0][j + 1] + w[0][j + 2];
        const float bot = w[2][j] + w[2][j + 1] + w[2][j + 2];
        const float mid = w[1][j] + w[1][j + 2];
        const float nbr = top + bot + mid;         // exact: <= 8 in fp32
        const float alive = w[1][j + 1];
        const float nxt = ((nbr == 3.0f) || (alive != 0.0f && nbr == 2.0f))
                              ? 1.0f : 0.0f;
        op[j] = nxt * keep;
    }

    *reinterpret_cast<float4*>(out + img + (size_t)y * W + c0) = o;
}

extern "C" void kernel_launch(void* const* d_in, const int* in_sizes, int n_in,
                              void* d_out, int out_size, void* d_ws, size_t ws_size,
                              hipStream_t stream) {
    const float* uni = (const float*)d_in[0];   // universe (8,1,2048,2048)
    const float* act = (const float*)d_in[1];   // action   (1,1,64,64)
    float* out  = (float*)d_out;
    float* flag = (float*)d_ws;                 // 1 float of scratch

    carle_flag_kernel<<<1, 256, 0, stream>>>(act, flag);
    carle_life_kernel<<<NIMG * H, 512, 0, stream>>>(uni, act, flag, out);
}

// Round 2
// 67.374 us; speedup vs baseline: 1.1827x; 1.1827x over previous
//
#include <hip/hip_runtime.h>

#define NIMG 8
#define H 2048
#define W 2048
#define AH 64
#define AW 64
#define PAD 992        // (W - AW) / 2
#define CH 32          // rows per wave
// strips: 8 per row of 256 cols; 64 row-chunks; 8 images -> 4096 waves -> 1024 blocks

// --- kernel 1: reset flag = (mean(action) == 1.0), one wave -----------------
__global__ void carle_flag_kernel(const float* __restrict__ act,
                                  float* __restrict__ flag) {
    const int lane = threadIdx.x;           // 0..63
    float s = 0.0f;
    const float4* a4 = reinterpret_cast<const float4*>(act);
    for (int i = lane; i < AH * AW / 4; i += 64) {
        float4 v = a4[i];
        s += v.x + v.y + v.z + v.w;
    }
    #pragma unroll
    for (int k = 32; k > 0; k >>= 1) s += __shfl_down(s, k);
    if (lane == 0) flag[0] = (s == (float)(AH * AW)) ? 1.0f : 0.0f;
}

// --- helpers ----------------------------------------------------------------
struct Row { float4 v; float hl, hr; };

__device__ __forceinline__ Row load_row(const float* __restrict__ uni,
                                        const float* __restrict__ act,
                                        size_t img, int r, int c, int lane, int s) {
    Row rw;
    rw.v = *reinterpret_cast<const float4*>(uni + img + (size_t)r * W + c);
    const bool arow = (r >= PAD && r < PAD + AH);
    if (arow && c >= PAD && c < PAD + AW) {
        const float* a = act + (r - PAD) * AW + (c - PAD);
        rw.v.x = (rw.v.x != a[0]) ? 1.0f : 0.0f;
        rw.v.y = (rw.v.y != a[1]) ? 1.0f : 0.0f;
        rw.v.z = (rw.v.z != a[2]) ? 1.0f : 0.0f;
        rw.v.w = (rw.v.w != a[3]) ? 1.0f : 0.0f;
    }
    rw.hl = 0.0f; rw.hr = 0.0f;
    if (lane == 0) {
        const int hc = (s - 1) & (W - 1);
        float x = uni[img + (size_t)r * W + hc];
        if (arow && hc >= PAD && hc < PAD + AW)
            x = (x != act[(r - PAD) * AW + (hc - PAD)]) ? 1.0f : 0.0f;
        rw.hl = x;
    }
    if (lane == 63) {
        const int hc = (s + 256) & (W - 1);
        float x = uni[img + (size_t)r * W + hc];
        if (arow && hc >= PAD && hc < PAD + AW)
            x = (x != act[(r - PAD) * AW + (hc - PAD)]) ? 1.0f : 0.0f;
        rw.hr = x;
    }
    return rw;
}

__device__ __forceinline__ float4 make_hs(const Row& r, int lane) {
    float left  = __shfl_up(r.v.w, 1);      // lane i-1's last col
    float right = __shfl_down(r.v.x, 1);    // lane i+1's first col
    if (lane == 0)  left  = r.hl;
    if (lane == 63) right = r.hr;
    float4 hs;
    hs.x = left   + r.v.x + r.v.y;
    hs.y = r.v.x  + r.v.y + r.v.z;
    hs.z = r.v.y  + r.v.z + r.v.w;
    hs.w = r.v.z  + r.v.w + right;
    return hs;
}

// --- kernel 2: one Life step, register-rolling strips, no LDS ---------------
__global__ __launch_bounds__(256) void carle_life_kernel(
        const float* __restrict__ uni,
        const float* __restrict__ act,
        const float* __restrict__ flag,
        float* __restrict__ out) {
    const int lane = threadIdx.x & 63;
    const int wv   = (blockIdx.x << 2) | (threadIdx.x >> 6);   // 0..4095
    const int n    = wv >> 9;                                  // image
    const int rem  = wv & 511;
    const int sx   = rem & 7;                                  // col strip
    const int sy   = rem >> 3;                                 // row chunk
    const int s    = sx << 8;                                  // col start
    const int y0   = sy * CH;
    const int c    = s + (lane << 2);
    const size_t img = (size_t)n * (size_t)H * (size_t)W;

    const float keep = (flag[0] == 1.0f) ? 0.0f : 1.0f;

    Row r0   = load_row(uni, act, img, (y0 - 1) & (H - 1), c, lane, s);
    Row r1   = load_row(uni, act, img, y0,                 c, lane, s);
    Row raw2 = load_row(uni, act, img, y0 + 1,             c, lane, s); // y0+1 <= 2016+1 < H

    float4 hs0 = make_hs(r0, lane);
    float4 hs1 = make_hs(r1, lane);
    float4 cen = r1.v;

    #pragma unroll 4
    for (int i = 0; i < CH; ++i) {
        const int y = y0 + i;
        Row rn;
        const bool more = (i < CH - 1);
        if (more)  // prefetch row y+2 for next iteration
            rn = load_row(uni, act, img, (y + 2) & (H - 1), c, lane, s);

        const float4 hs2 = make_hs(raw2, lane);

        float4 o;
        {
            const float nx = hs0.x + hs1.x + hs2.x - cen.x;
            o.x = (nx == 3.0f || (cen.x != 0.0f && nx == 2.0f)) ? keep : 0.0f;
            const float ny = hs0.y + hs1.y + hs2.y - cen.y;
            o.y = (ny == 3.0f || (cen.y != 0.0f && ny == 2.0f)) ? keep : 0.0f;
            const float nz = hs0.z + hs1.z + hs2.z - cen.z;
            o.z = (nz == 3.0f || (cen.z != 0.0f && nz == 2.0f)) ? keep : 0.0f;
            const float nw = hs0.w + hs1.w + hs2.w - cen.w;
            o.w = (nw == 3.0f || (cen.w != 0.0f && nw == 2.0f)) ? keep : 0.0f;
        }
        *reinterpret_cast<float4*>(out + img + (size_t)y * W + c) = o;

        hs0 = hs1; hs1 = hs2; cen = raw2.v;
        if (more) raw2 = rn;
    }
}

extern "C" void kernel_launch(void* const* d_in, const int* in_sizes, int n_in,
                              void* d_out, int out_size, void* d_ws, size_t ws_size,
                              hipStream_t stream) {
    const float* uni = (const float*)d_in[0];   // (8,1,2048,2048) f32
    const float* act = (const float*)d_in[1];   // (1,1,64,64) f32
    float* outp = (float*)d_out;
    float* flag = (float*)d_ws;

    carle_flag_kernel<<<1, 64, 0, stream>>>(act, flag);
    carle_life_kernel<<<(NIMG * 8 * (H / CH)) / 4, 256, 0, stream>>>(uni, act, flag, outp);
}

// Round 3
// 66.836 us; speedup vs baseline: 1.1923x; 1.0081x over previous
//
#include <hip/hip_runtime.h>

#define NIMG 8
#define H 2048
#define W 2048
#define AH 64
#define AW 64
#define PAD 992        // (W - AW) / 2
#define CH 16          // rows per wave -> 8192 waves -> 8 waves/SIMD

typedef float f4 __attribute__((ext_vector_type(4)));

// --- kernel 1: reset flag = (mean(action) == 1.0) ---------------------------
__global__ __launch_bounds__(1024) void carle_flag_kernel(
        const float* __restrict__ act, float* __restrict__ flag) {
    __shared__ float sm[16];
    const int t = threadIdx.x;                 // 0..1023, 1024 float4 = 4096 elems
    const f4 v = reinterpret_cast<const f4*>(act)[t];
    float s = v.x + v.y + v.z + v.w;
    #pragma unroll
    for (int k = 32; k > 0; k >>= 1) s += __shfl_down(s, k);
    if ((t & 63) == 0) sm[t >> 6] = s;
    __syncthreads();
    if (t < 16) {
        float x = sm[t];
        #pragma unroll
        for (int k = 8; k > 0; k >>= 1) x += __shfl_down(x, k);
        if (t == 0) flag[0] = (x == (float)(AH * AW)) ? 1.0f : 0.0f;
    }
}

// --- helpers ----------------------------------------------------------------
struct Row { f4 v; float hl, hr; };

__device__ __forceinline__ Row load_row(const float* __restrict__ uni,
                                        const float* __restrict__ act,
                                        size_t img, int r, int c, int lane, int s) {
    r &= (H - 1);
    Row rw;
    rw.v = *reinterpret_cast<const f4*>(uni + img + (size_t)r * W + c);
    const bool arow = (r >= PAD && r < PAD + AH);
    if (arow && c >= PAD && c < PAD + AW) {
        const float* a = act + (r - PAD) * AW + (c - PAD);
        rw.v.x = (rw.v.x != a[0]) ? 1.0f : 0.0f;
        rw.v.y = (rw.v.y != a[1]) ? 1.0f : 0.0f;
        rw.v.z = (rw.v.z != a[2]) ? 1.0f : 0.0f;
        rw.v.w = (rw.v.w != a[3]) ? 1.0f : 0.0f;
    }
    rw.hl = 0.0f; rw.hr = 0.0f;
    if (lane == 0) {
        const int hc = (s - 1) & (W - 1);
        float x = uni[img + (size_t)r * W + hc];
        if (arow && hc >= PAD && hc < PAD + AW)
            x = (x != act[(r - PAD) * AW + (hc - PAD)]) ? 1.0f : 0.0f;
        rw.hl = x;
    }
    if (lane == 63) {
        const int hc = (s + 256) & (W - 1);
        float x = uni[img + (size_t)r * W + hc];
        if (arow && hc >= PAD && hc < PAD + AW)
            x = (x != act[(r - PAD) * AW + (hc - PAD)]) ? 1.0f : 0.0f;
        rw.hr = x;
    }
    return rw;
}

__device__ __forceinline__ f4 make_hs(const Row& r, int lane) {
    float left  = __shfl_up(r.v.w, 1);
    float right = __shfl_down(r.v.x, 1);
    if (lane == 0)  left  = r.hl;
    if (lane == 63) right = r.hr;
    f4 hs;
    hs.x = left  + r.v.x + r.v.y;
    hs.y = r.v.x + r.v.y + r.v.z;
    hs.z = r.v.y + r.v.z + r.v.w;
    hs.w = r.v.z + r.v.w + right;
    return hs;
}

__device__ __forceinline__ f4 life(const f4 a, const f4 b, const f4 c,
                                   const f4 cen, float keep) {
    f4 o;
    const float nx = a.x + b.x + c.x - cen.x;
    o.x = (nx == 3.0f || (cen.x != 0.0f && nx == 2.0f)) ? keep : 0.0f;
    const float ny = a.y + b.y + c.y - cen.y;
    o.y = (ny == 3.0f || (cen.y != 0.0f && ny == 2.0f)) ? keep : 0.0f;
    const float nz = a.z + b.z + c.z - cen.z;
    o.z = (nz == 3.0f || (cen.z != 0.0f && nz == 2.0f)) ? keep : 0.0f;
    const float nw = a.w + b.w + c.w - cen.w;
    o.w = (nw == 3.0f || (cen.w != 0.0f && nw == 2.0f)) ? keep : 0.0f;
    return o;
}

// --- kernel 2: one Life step, register-rolling strips, pair-pipelined -------
__global__ __launch_bounds__(256, 8) void carle_life_kernel(
        const float* __restrict__ uni,
        const float* __restrict__ act,
        const float* __restrict__ flag,
        float* __restrict__ out) {
    const int lane = threadIdx.x & 63;
    const int wv   = (blockIdx.x << 2) | (threadIdx.x >> 6);   // 0..8191
    const int n    = wv >> 10;                                 // image (1024 waves/img)
    const int rem  = wv & 1023;
    const int sx   = rem & 7;                                  // col strip
    const int sy   = rem >> 3;                                 // row chunk 0..127
    const int s    = sx << 8;
    const int y0   = sy * CH;
    const int c    = s + (lane << 2);
    const size_t img = (size_t)n * (size_t)H * (size_t)W;

    const float keep = (flag[0] == 1.0f) ? 0.0f : 1.0f;

    Row rm1 = load_row(uni, act, img, y0 - 1, c, lane, s);
    Row r0  = load_row(uni, act, img, y0,     c, lane, s);
    Row R1  = load_row(uni, act, img, y0 + 1, c, lane, s);
    Row R2  = load_row(uni, act, img, y0 + 2, c, lane, s);

    f4 hsA = make_hs(rm1, lane);   // hs(y-1)
    f4 hsB = make_hs(r0, lane);    // hs(y)
    f4 va  = r0.v;                 // v(y)

    #pragma unroll
    for (int i = 0; i < CH; i += 2) {
        Row p0, p1;
        if (i < CH - 2) {
            p0 = load_row(uni, act, img, y0 + i + 3, c, lane, s);
            p1 = load_row(uni, act, img, y0 + i + 4, c, lane, s);
        }
        const f4 hsC = make_hs(R1, lane);
        const f4 o0  = life(hsA, hsB, hsC, va, keep);
        __builtin_nontemporal_store(o0,
            reinterpret_cast<f4*>(out + img + (size_t)(y0 + i) * W + c));
        const f4 hsD = make_hs(R2, lane);
        const f4 o1  = life(hsB, hsC, hsD, R1.v, keep);
        __builtin_nontemporal_store(o1,
            reinterpret_cast<f4*>(out + img + (size_t)(y0 + i + 1) * W + c));
        hsA = hsC; hsB = hsD; va = R2.v;
        if (i < CH - 2) { R1 = p0; R2 = p1; }
    }
}

extern "C" void kernel_launch(void* const* d_in, const int* in_sizes, int n_in,
                              void* d_out, int out_size, void* d_ws, size_t ws_size,
                              hipStream_t stream) {
    const float* uni = (const float*)d_in[0];   // (8,1,2048,2048) f32
    const float* act = (const float*)d_in[1];   // (1,1,64,64) f32
    float* outp = (float*)d_out;
    float* flag = (float*)d_ws;

    carle_flag_kernel<<<1, 1024, 0, stream>>>(act, flag);
    carle_life_kernel<<<NIMG * 8 * (H / CH) / 4, 256, 0, stream>>>(uni, act, flag, outp);
}

// Round 4
// 52.328 us; speedup vs baseline: 1.5228x; 1.2773x over previous
//
#include <hip/hip_runtime.h>

#define NIMG 8
#define H 2048
#define W 2048
#define AH 64
#define AW 64
#define PAD 992        // (W - AW) / 2
#define CH 16          // rows per wave -> 8192 waves -> 8/SIMD

typedef float f4 __attribute__((ext_vector_type(4)));

// read lane k of a float (uniform broadcast, no exec dependence)
__device__ __forceinline__ float rl(float v, int k) {
    return __int_as_float(__builtin_amdgcn_readlane(__float_as_int(v), k));
}

// load one float4 of a (wrapped) row, with action-XOR applied
__device__ __forceinline__ f4 load_row(const float* __restrict__ uni,
                                       const float* __restrict__ act,
                                       size_t img, int r, int c) {
    r &= (H - 1);
    f4 v = *reinterpret_cast<const f4*>(uni + img + (size_t)r * W + c);
    if (r >= PAD && r < PAD + AH && c >= PAD && c < PAD + AW) {
        const float* a = act + (r - PAD) * AW + (c - PAD);
        v.x = (v.x != a[0]) ? 1.0f : 0.0f;
        v.y = (v.y != a[1]) ? 1.0f : 0.0f;
        v.z = (v.z != a[2]) ? 1.0f : 0.0f;
        v.w = (v.w != a[3]) ? 1.0f : 0.0f;
    }
    return v;
}

__device__ __forceinline__ f4 make_hs(f4 v, int lane, float hl, float hr) {
    float left  = __shfl_up(v.w, 1);
    float right = __shfl_down(v.x, 1);
    if (lane == 0)  left  = hl;
    if (lane == 63) right = hr;
    f4 hs;
    hs.x = left  + v.x + v.y;
    hs.y = v.x + v.y + v.z;
    hs.z = v.y + v.z + v.w;
    hs.w = v.z + v.w + right;
    return hs;
}

// next = (nbr==3) || (nbr==2 && alive)  <=>  |nbr - 3 + 0.5*alive| <= 0.5 (exact)
__device__ __forceinline__ f4 life(f4 a, f4 b, f4 c, f4 cen, float keep) {
    f4 nbr3 = a + b + c - cen;          // = nbr (includes center) - center
    nbr3.x -= 3.0f; nbr3.y -= 3.0f; nbr3.z -= 3.0f; nbr3.w -= 3.0f;
    f4 o;
    o.x = (__builtin_fabsf(__builtin_fmaf(0.5f, cen.x, nbr3.x)) <= 0.5f) ? keep : 0.0f;
    o.y = (__builtin_fabsf(__builtin_fmaf(0.5f, cen.y, nbr3.y)) <= 0.5f) ? keep : 0.0f;
    o.z = (__builtin_fabsf(__builtin_fmaf(0.5f, cen.z, nbr3.z)) <= 0.5f) ? keep : 0.0f;
    o.w = (__builtin_fabsf(__builtin_fmaf(0.5f, cen.w, nbr3.w)) <= 0.5f) ? keep : 0.0f;
    return o;
}

__global__ __launch_bounds__(256, 8) void carle_life_kernel(
        const float* __restrict__ uni,
        const float* __restrict__ act,
        float* __restrict__ out) {
    __shared__ float red[4];
    const int t    = threadIdx.x;
    const int lane = t & 63;
    const int wvid = t >> 6;

    const int wv  = (blockIdx.x << 2) | wvid;   // 0..8191
    const int n   = wv >> 10;                   // image
    const int rem = wv & 1023;
    const int sx  = rem & 7;                    // col strip (256 wide)
    const int sy  = rem >> 3;                   // row chunk (16 tall)
    const int strip = sx << 8;
    const int y0  = sy * CH;
    const int c   = strip + (lane << 2);
    const size_t img = (size_t)n * (size_t)H * (size_t)W;

    // ---- batched halo columns: lanes 0..17 left col, lanes 32..49 right ----
    const int hr   = lane & 31;
    const int hcol = (lane < 32) ? ((strip - 1) & (W - 1))
                                 : ((strip + 256) & (W - 1));
    float halo = 0.0f;
    if (hr < CH + 2) {
        const int r = (y0 - 1 + hr) & (H - 1);
        float x = uni[img + (size_t)r * W + hcol];
        if (r >= PAD && r < PAD + AH && hcol >= PAD && hcol < PAD + AW)
            x = (x != act[(r - PAD) * AW + (hcol - PAD)]) ? 1.0f : 0.0f;
        halo = x;
    }

    // ---- preload 6 rows (k = 0..5 i.e. y0-1 .. y0+4) ----
    f4 v0 = load_row(uni, act, img, y0 - 1, c);
    f4 v1 = load_row(uni, act, img, y0,     c);
    f4 v2 = load_row(uni, act, img, y0 + 1, c);
    f4 v3 = load_row(uni, act, img, y0 + 2, c);
    f4 v4 = load_row(uni, act, img, y0 + 3, c);
    f4 v5 = load_row(uni, act, img, y0 + 4, c);

    // ---- fused reset flag: sum(action) == 4096 ----
    {
        const f4* a4 = reinterpret_cast<const f4*>(act);
        float s = 0.0f;
        #pragma unroll
        for (int j = 0; j < 4; ++j) {
            f4 a = a4[t * 4 + j];
            s += a.x + a.y + a.z + a.w;
        }
        #pragma unroll
        for (int k = 32; k > 0; k >>= 1) s += __shfl_down(s, k);
        if (lane == 0) red[wvid] = s;
    }
    __syncthreads();
    const float keep =
        ((red[0] + red[1] + red[2] + red[3]) == (float)(AH * AW)) ? 0.0f : 1.0f;

    // ---- steady-state: 2 rows per iter, lookahead 2 iters ----
    f4 hsA = make_hs(v0, lane, rl(halo, 0), rl(halo, 32));
    f4 hsB = make_hs(v1, lane, rl(halo, 1), rl(halo, 33));
    f4 cen = v1;

    #pragma unroll
    for (int i = 0; i < CH; i += 2) {
        f4 p0, p1;
        const bool ld0 = (i + 6 < CH + 2);
        const bool ld1 = (i + 7 < CH + 2);
        if (ld0) p0 = load_row(uni, act, img, y0 + i + 5, c);  // k=i+6
        if (ld1) p1 = load_row(uni, act, img, y0 + i + 6, c);  // k=i+7

        const f4 hsC = make_hs(v2, lane, rl(halo, i + 2), rl(halo, 32 + i + 2));
        const f4 o0  = life(hsA, hsB, hsC, cen, keep);
        __builtin_nontemporal_store(o0,
            reinterpret_cast<f4*>(out + img + (size_t)(y0 + i) * W + c));

        const f4 hsD = make_hs(v3, lane, rl(halo, i + 3), rl(halo, 32 + i + 3));
        const f4 o1  = life(hsB, hsC, hsD, v2, keep);
        __builtin_nontemporal_store(o1,
            reinterpret_cast<f4*>(out + img + (size_t)(y0 + i + 1) * W + c));

        hsA = hsC; hsB = hsD; cen = v3;
        v2 = v4; v3 = v5;
        if (ld0) v4 = p0;
        if (ld1) v5 = p1;
    }
}

extern "C" void kernel_launch(void* const* d_in, const int* in_sizes, int n_in,
                              void* d_out, int out_size, void* d_ws, size_t ws_size,
                              hipStream_t stream) {
    const float* uni = (const float*)d_in[0];   // (8,1,2048,2048) f32
    const float* act = (const float*)d_in[1];   // (1,1,64,64) f32
    float* outp = (float*)d_out;
    (void)d_ws;

    carle_life_kernel<<<NIMG * 8 * (H / CH) / 4, 256, 0, stream>>>(uni, act, outp);
}

// Round 5
// 46.974 us; speedup vs baseline: 1.6964x; 1.1140x over previous
//
#include <hip/hip_runtime.h>

#define NIMG 8
#define H 2048
#define W 2048
#define AH 64
#define AW 64
#define PAD 992        // (W - AW) / 2
#define CH 16          // rows per wave -> 8192 waves -> 8/SIMD

typedef float f4 __attribute__((ext_vector_type(4)));

__device__ __forceinline__ float rl(float v, int k) {
    return __int_as_float(__builtin_amdgcn_readlane(__float_as_int(v), k));
}

// load one float4 of a (wrapped) row, with action-XOR applied
__device__ __forceinline__ f4 load_row(const float* __restrict__ uni,
                                       const float* __restrict__ act,
                                       size_t img, int r, int c) {
    r &= (H - 1);
    f4 v = *reinterpret_cast<const f4*>(uni + img + (size_t)r * W + c);
    if (r >= PAD && r < PAD + AH && c >= PAD && c < PAD + AW) {
        const float* a = act + (r - PAD) * AW + (c - PAD);
        v.x = (v.x != a[0]) ? 1.0f : 0.0f;
        v.y = (v.y != a[1]) ? 1.0f : 0.0f;
        v.z = (v.z != a[2]) ? 1.0f : 0.0f;
        v.w = (v.w != a[3]) ? 1.0f : 0.0f;
    }
    return v;
}

__device__ __forceinline__ f4 make_hs(f4 v, int lane, float hl, float hr) {
    float left  = __shfl_up(v.w, 1);
    float right = __shfl_down(v.x, 1);
    if (lane == 0)  left  = hl;
    if (lane == 63) right = hr;
    f4 hs;
    hs.x = left  + v.x + v.y;
    hs.y = v.x + v.y + v.z;
    hs.z = v.y + v.z + v.w;
    hs.w = v.z + v.w + right;
    return hs;
}

// next = (nbr==3) || (nbr==2 && alive)  <=>  |nbr - 3 + 0.5*alive| <= 0.5 (exact)
__device__ __forceinline__ f4 life(f4 a, f4 b, f4 c, f4 cen, float keep) {
    f4 nbr3 = a + b + c - cen;
    nbr3.x -= 3.0f; nbr3.y -= 3.0f; nbr3.z -= 3.0f; nbr3.w -= 3.0f;
    f4 o;
    o.x = (__builtin_fabsf(__builtin_fmaf(0.5f, cen.x, nbr3.x)) <= 0.5f) ? keep : 0.0f;
    o.y = (__builtin_fabsf(__builtin_fmaf(0.5f, cen.y, nbr3.y)) <= 0.5f) ? keep : 0.0f;
    o.z = (__builtin_fabsf(__builtin_fmaf(0.5f, cen.z, nbr3.z)) <= 0.5f) ? keep : 0.0f;
    o.w = (__builtin_fabsf(__builtin_fmaf(0.5f, cen.w, nbr3.w)) <= 0.5f) ? keep : 0.0f;
    return o;
}

__global__ __launch_bounds__(256, 8) void carle_life_kernel(
        const float* __restrict__ uni,
        const float* __restrict__ act,
        float* __restrict__ out) {
    __shared__ float red[4];
    const int t    = threadIdx.x;
    const int lane = t & 63;
    const int wvid = t >> 6;

    // XCD-contiguous swizzle: each XCD (bid&7) owns one image, walked in sy order
    const int bid = blockIdx.x;
    const int sb  = ((bid & 7) << 8) | (bid >> 3);    // bijective on [0,2048)
    const int wv  = (sb << 2) | wvid;                 // 0..8191
    const int n   = wv >> 10;                         // image
    const int rem = wv & 1023;
    const int sx  = rem & 7;                          // col strip (256 wide)
    const int sy  = rem >> 3;                         // row chunk (16 tall)
    const int strip = sx << 8;
    const int y0  = sy * CH;
    const int c   = strip + (lane << 2);
    const size_t img = (size_t)n * (size_t)H * (size_t)W;

    // ---- preload 7 rows (k = 0..6, rows y0-1 .. y0+5): max head start ----
    f4 vA = load_row(uni, act, img, y0 - 1, c);
    f4 vB = load_row(uni, act, img, y0,     c);
    f4 b1 = load_row(uni, act, img, y0 + 1, c);
    f4 b2 = load_row(uni, act, img, y0 + 2, c);
    f4 b3 = load_row(uni, act, img, y0 + 3, c);
    f4 b4 = load_row(uni, act, img, y0 + 4, c);
    f4 b5 = load_row(uni, act, img, y0 + 5, c);

    // ---- batched halo columns: lanes 0..17 left col, lanes 32..49 right ----
    const int hr   = lane & 31;
    const int hcol = (lane < 32) ? ((strip - 1) & (W - 1))
                                 : ((strip + 256) & (W - 1));
    float halo = 0.0f;
    if (hr < CH + 2) {
        const int r = (y0 - 1 + hr) & (H - 1);
        float x = uni[img + (size_t)r * W + hcol];
        if (r >= PAD && r < PAD + AH && hcol >= PAD && hcol < PAD + AW)
            x = (x != act[(r - PAD) * AW + (hcol - PAD)]) ? 1.0f : 0.0f;
        halo = x;
    }

    // ---- fused reset flag: sum(action) == 4096 (overlaps the row loads) ----
    {
        const f4* a4 = reinterpret_cast<const f4*>(act);
        float s = 0.0f;
        #pragma unroll
        for (int j = 0; j < 4; ++j) {
            f4 a = a4[t * 4 + j];
            s += a.x + a.y + a.z + a.w;
        }
        #pragma unroll
        for (int k = 32; k > 0; k >>= 1) s += __shfl_down(s, k);
        if (lane == 0) red[wvid] = s;
    }
    __syncthreads();
    const float keep =
        ((red[0] + red[1] + red[2] + red[3]) == (float)(AH * AW)) ? 0.0f : 1.0f;

    // ---- steady state: 1 row/iter, prefetch distance 5 (≈6 loads in flight)
    f4 hsA = make_hs(vA, lane, rl(halo, 0), rl(halo, 32));
    f4 hsB = make_hs(vB, lane, rl(halo, 1), rl(halo, 33));
    f4 cen = vB;

    #pragma unroll
    for (int i = 0; i < CH; ++i) {
        f4 bn;
        const bool ld = (i + 7 < CH + 2);              // row k=i+7 exists
        if (ld) bn = load_row(uni, act, img, y0 + i + 6, c);

        const f4 hsC = make_hs(b1, lane, rl(halo, i + 2), rl(halo, 32 + i + 2));
        const f4 o   = life(hsA, hsB, hsC, cen, keep);
        __builtin_nontemporal_store(o,
            reinterpret_cast<f4*>(out + img + (size_t)(y0 + i) * W + c));

        hsA = hsB; hsB = hsC; cen = b1;
        b1 = b2; b2 = b3; b3 = b4; b4 = b5;
        if (ld) b5 = bn;
    }
}

extern "C" void kernel_launch(void* const* d_in, const int* in_sizes, int n_in,
                              void* d_out, int out_size, void* d_ws, size_t ws_size,
                              hipStream_t stream) {
    const float* uni = (const float*)d_in[0];   // (8,1,2048,2048) f32
    const float* act = (const float*)d_in[1];   // (1,1,64,64) f32
    float* outp = (float*)d_out;
    (void)d_ws;

    carle_life_kernel<<<NIMG * 8 * (H / CH) / 4, 256, 0, stream>>>(uni, act, outp);
}